// Round 16
// baseline (285.388 us; speedup 1.0000x reference)
//
#include <hip/hip_runtime.h>

#define NEG_SLOPE 0.2f
#define INVLN2 1.44269504f

// ---------- dual-output fp32 GEMM: Y1=X@W1, Y2=X@W2 — TLP-first ----------
template<int K, int H, int BK, int BM, int NT>
__global__ __launch_bounds__(NT) void gemm2_kernel(const float* __restrict__ X,
                                                   const float* __restrict__ W1,
                                                   const float* __restrict__ W2,
                                                   float* __restrict__ Y1,
                                                   float* __restrict__ Y2, int n) {
  constexpr int CG = H / 4;   // col groups
  constexpr int RG = BM / 4;  // row groups
  static_assert(CG * RG == NT, "thread grid mismatch");
  __shared__ alignas(16) float Xs[BK][BM + 4];
  __shared__ alignas(16) float Ws1[BK][H];
  __shared__ alignas(16) float Ws2[BK][H];
  const int tid = threadIdx.x;
  const int row0 = blockIdx.x * BM;
  const int cg = tid % CG, rg = tid / CG;
  float acc1[4][4] = {};
  float acc2[4][4] = {};

  for (int kc = 0; kc < K; kc += BK) {
    for (int i = tid; i < BK * H / 4; i += NT) {
      ((float4*)&Ws1[0][0])[i] = ((const float4*)(W1 + (size_t)kc * H))[i];
      ((float4*)&Ws2[0][0])[i] = ((const float4*)(W2 + (size_t)kc * H))[i];
    }
    for (int i = tid; i < BM * (BK / 4); i += NT) {
      int r = i / (BK / 4), kq = i % (BK / 4);
      int gr = row0 + r; if (gr >= n) gr = n - 1;
      float4 v = ((const float4*)(X + (size_t)gr * K + kc))[kq];
      Xs[kq * 4 + 0][r] = v.x;
      Xs[kq * 4 + 1][r] = v.y;
      Xs[kq * 4 + 2][r] = v.z;
      Xs[kq * 4 + 3][r] = v.w;
    }
    __syncthreads();
#pragma unroll 8
    for (int k = 0; k < BK; ++k) {
      float4 xa = *(const float4*)&Xs[k][rg * 4];
      float4 wa = *(const float4*)&Ws1[k][cg * 4];
      float4 wb = *(const float4*)&Ws2[k][cg * 4];
#pragma unroll
      for (int i = 0; i < 4; ++i) {
        float xi = (i == 0) ? xa.x : (i == 1) ? xa.y : (i == 2) ? xa.z : xa.w;
        acc1[i][0] = fmaf(xi, wa.x, acc1[i][0]);
        acc1[i][1] = fmaf(xi, wa.y, acc1[i][1]);
        acc1[i][2] = fmaf(xi, wa.z, acc1[i][2]);
        acc1[i][3] = fmaf(xi, wa.w, acc1[i][3]);
        acc2[i][0] = fmaf(xi, wb.x, acc2[i][0]);
        acc2[i][1] = fmaf(xi, wb.y, acc2[i][1]);
        acc2[i][2] = fmaf(xi, wb.z, acc2[i][2]);
        acc2[i][3] = fmaf(xi, wb.w, acc2[i][3]);
      }
    }
    __syncthreads();
  }
  const int c0 = cg * 4;
#pragma unroll
  for (int i = 0; i < 4; ++i) {
    int gr = row0 + rg * 4 + i;
    if (gr < n) {
      *(float4*)(Y1 + (size_t)gr * H + c0) = make_float4(acc1[i][0], acc1[i][1], acc1[i][2], acc1[i][3]);
      *(float4*)(Y2 + (size_t)gr * H + c0) = make_float4(acc2[i][0], acc2[i][1], acc2[i][2], acc2[i][3]);
    }
  }
}

// ---------- CSR build: histogram of dst ----------
__global__ void hist_kernel(const int* __restrict__ ei, int* __restrict__ deg, int nE, int nN) {
  int t = blockIdx.x * blockDim.x + threadIdx.x;
  if (t >= nE + nN) return;
  int d = (t < nE) ? ei[nE + t] : (t - nE);
  atomicAdd(&deg[d], 1);
}

// ---------- parallel scan, step 1: per-256-chunk sums ----------
__global__ void chunk_sum_kernel(const int* __restrict__ deg, int* __restrict__ psum, int n) {
  int c = blockIdx.x;
  int i = c * 256 + threadIdx.x;
  int lane = threadIdx.x & 63, wid = threadIdx.x >> 6;
  int v = (i < n) ? deg[i] : 0;
#pragma unroll
  for (int off = 32; off; off >>= 1) v += __shfl_xor(v, off);
  __shared__ int ws[4];
  if (lane == 0) ws[wid] = v;
  __syncthreads();
  if (threadIdx.x == 0) psum[c] = ws[0] + ws[1] + ws[2] + ws[3];
}

// ---------- block-wide inclusive scan helper (256 threads) ----------
__device__ __forceinline__ int block_incl_scan_256(int v) {
  int lane = threadIdx.x & 63, wid = threadIdx.x >> 6;
#pragma unroll
  for (int off = 1; off < 64; off <<= 1) {
    int t = __shfl_up(v, off);
    if (lane >= off) v += t;
  }
  __shared__ int wsum[4];
  if (lane == 63) wsum[wid] = v;
  __syncthreads();
  int add = 0;
  for (int w = 0; w < wid; ++w) add += wsum[w];
  return v + add;
}

// ---------- parallel scan, step 2: inclusive scan of chunk sums (nc <= 256) ----------
__global__ void scan_chunks_kernel(int* __restrict__ psum, int nc) {
  int i = threadIdx.x;
  int v = (i < nc) ? psum[i] : 0;
  int incl = block_incl_scan_256(v);
  if (i < nc) psum[i] = incl;
}

// ---------- parallel scan, step 3: intra-chunk scan + chunk offset -> rowptr ----------
__global__ void scan_final_kernel(const int* __restrict__ deg, const int* __restrict__ psum,
                                  int* __restrict__ rowptr, int n) {
  int c = blockIdx.x;
  int i = c * 256 + threadIdx.x;
  int v = (i < n) ? deg[i] : 0;
  int incl = block_incl_scan_256(v);
  int off = (c > 0) ? psum[c - 1] : 0;
  if (i < n) rowptr[i + 1] = off + incl;
  if (i == 0) rowptr[0] = 0;
}

// ---------- CSR build: fill src ids into dst buckets ----------
__global__ void fill_kernel(const int* __restrict__ ei, int* __restrict__ cnt,
                            const int* __restrict__ rowptr, int* __restrict__ ebuf,
                            int nE, int nN) {
  int t = blockIdx.x * blockDim.x + threadIdx.x;
  if (t >= nE + nN) return;
  int s, d;
  if (t < nE) { s = ei[t]; d = ei[nE + t]; } else { s = t - nE; d = s; }
  int pos = rowptr[d] + atomicAdd(&cnt[d], 1);
  ebuf[pos] = s;
}

// ---------- fused GATv2 layer: wave per dst, 4x16-lane edge groups ----------
// Round-13 structure (1 edge/group-iter, 32 VGPR, occupancy-bound optimum)
// + register-neutral exp2 trick: att pre-scaled by 1/ln2, exp2f everywhere
// (v_exp_f32 natively computes 2^x).
template<int H>
__global__ void gat_fused_kernel(const float* __restrict__ XL, const float* __restrict__ XR,
                                 const int* __restrict__ rowptr, const int* __restrict__ ebuf,
                                 const float* __restrict__ att, const float* __restrict__ bias,
                                 float* __restrict__ out, int nN) {
  constexpr bool HAS2 = (H > 64);
  int lane = threadIdx.x & 63;
  int wid = threadIdx.x >> 6;
  int d = blockIdx.x * (blockDim.x >> 6) + wid;
  if (d >= nN) return;
  int g = lane >> 4;   // edge group 0..3
  int ll = lane & 15;  // lane within group
  const int cA = ll * 4;
  const int cB = 64 + ll * 2;

  const float* xrrow = XR + (size_t)d * H;
  float4 xr4 = *(const float4*)(xrrow + cA);
  float4 a4 = *(const float4*)(att + cA);
  a4.x *= INVLN2; a4.y *= INVLN2; a4.z *= INVLN2; a4.w *= INVLN2;
  float4 s4 = make_float4(a4.x * NEG_SLOPE, a4.y * NEG_SLOPE, a4.z * NEG_SLOPE, a4.w * NEG_SLOPE);
  float2 xr2 = make_float2(0.f, 0.f), a2 = make_float2(0.f, 0.f), s2 = make_float2(0.f, 0.f);
  if constexpr (HAS2) {
    xr2 = *(const float2*)(xrrow + cB);
    a2 = *(const float2*)(att + cB);
    a2.x *= INVLN2; a2.y *= INVLN2;
    s2 = make_float2(a2.x * NEG_SLOPE, a2.y * NEG_SLOPE);
  }

  float m = -1e30f, den = 0.f;  // m in log2 domain
  float4 o4 = make_float4(0.f, 0.f, 0.f, 0.f);
  float2 o2 = make_float2(0.f, 0.f);

  int beg = rowptr[d], end = rowptr[d + 1];
  int i = beg + g;
  int s = (i < end) ? ebuf[i] : 0;
  while (i < end) {
    int inext = i + 4;
    int snext = (inext < end) ? ebuf[inext] : 0;
    const float* R = XL + (size_t)s * H;
    float4 x4 = *(const float4*)(R + cA);
    float2 x2 = make_float2(0.f, 0.f);
    if constexpr (HAS2) x2 = *(const float2*)(R + cB);
    float f, p;
    f = x4.x + xr4.x; p = fmaf(fmaxf(f, 0.f), a4.x, fminf(f, 0.f) * s4.x);
    f = x4.y + xr4.y; p = fmaf(fmaxf(f, 0.f), a4.y, fmaf(fminf(f, 0.f), s4.y, p));
    f = x4.z + xr4.z; p = fmaf(fmaxf(f, 0.f), a4.z, fmaf(fminf(f, 0.f), s4.z, p));
    f = x4.w + xr4.w; p = fmaf(fmaxf(f, 0.f), a4.w, fmaf(fminf(f, 0.f), s4.w, p));
    if constexpr (HAS2) {
      f = x2.x + xr2.x; p = fmaf(fmaxf(f, 0.f), a2.x, fmaf(fminf(f, 0.f), s2.x, p));
      f = x2.y + xr2.y; p = fmaf(fmaxf(f, 0.f), a2.y, fmaf(fminf(f, 0.f), s2.y, p));
    }
    p += __shfl_xor(p, 1);
    p += __shfl_xor(p, 2);
    p += __shfl_xor(p, 4);
    p += __shfl_xor(p, 8);
    if (p > m) {
      float scl = exp2f(m - p);
      den *= scl;
      o4.x *= scl; o4.y *= scl; o4.z *= scl; o4.w *= scl;
      if constexpr (HAS2) { o2.x *= scl; o2.y *= scl; }
      m = p;
    }
    float w = exp2f(p - m);
    den += w;
    o4.x = fmaf(w, x4.x, o4.x); o4.y = fmaf(w, x4.y, o4.y);
    o4.z = fmaf(w, x4.z, o4.z); o4.w = fmaf(w, x4.w, o4.w);
    if constexpr (HAS2) { o2.x = fmaf(w, x2.x, o2.x); o2.y = fmaf(w, x2.y, o2.y); }
    i = inext;
    s = snext;
  }

  // merge the 4 groups (flash-style, log2 domain), xor 16 then xor 32
#pragma unroll
  for (int msk = 16; msk <= 32; msk <<= 1) {
    float m2 = __shfl_xor(m, msk);
    float den2 = __shfl_xor(den, msk);
    float q0 = __shfl_xor(o4.x, msk), q1 = __shfl_xor(o4.y, msk);
    float q2 = __shfl_xor(o4.z, msk), q3 = __shfl_xor(o4.w, msk);
    float q4 = 0.f, q5 = 0.f;
    if constexpr (HAS2) { q4 = __shfl_xor(o2.x, msk); q5 = __shfl_xor(o2.y, msk); }
    float M = fmaxf(m, m2);
    float sa = exp2f(m - M), sb = exp2f(m2 - M);
    den = den * sa + den2 * sb;
    o4.x = o4.x * sa + q0 * sb; o4.y = o4.y * sa + q1 * sb;
    o4.z = o4.z * sa + q2 * sb; o4.w = o4.w * sa + q3 * sb;
    if constexpr (HAS2) { o2.x = o2.x * sa + q4 * sb; o2.y = o2.y * sa + q5 * sb; }
    m = M;
  }

  if (g == 0) {
    float inv = 1.f / (den + 1e-16f);
    float4 b4 = *(const float4*)(bias + cA);
    float4 y;
    y.x = fmaf(o4.x, inv, b4.x); y.x = y.x > 0.f ? y.x : 0.f;
    y.y = fmaf(o4.y, inv, b4.y); y.y = y.y > 0.f ? y.y : 0.f;
    y.z = fmaf(o4.z, inv, b4.z); y.z = y.z > 0.f ? y.z : 0.f;
    y.w = fmaf(o4.w, inv, b4.w); y.w = y.w > 0.f ? y.w : 0.f;
    *(float4*)(out + (size_t)d * H + cA) = y;
    if constexpr (HAS2) {
      float2 b2 = *(const float2*)(bias + cB);
      float2 z;
      z.x = fmaf(o2.x, inv, b2.x); z.x = z.x > 0.f ? z.x : 0.f;
      z.y = fmaf(o2.y, inv, b2.y); z.y = z.y > 0.f ? z.y : 0.f;
      *(float2*)(out + (size_t)d * H + cB) = z;
    }
  }
}

// ---------- out[l] = sum_k hs[k]*hd[k]*(Wp[k,0]+Wp[k,1]) + bp0+bp1 ----------
__global__ void predict_kernel(const float* __restrict__ h, const int* __restrict__ eli,
                               const float* __restrict__ Wp, const float* __restrict__ bp,
                               float* __restrict__ out, int L) {
  int l = blockIdx.x * blockDim.x + threadIdx.x;
  if (l >= L) return;
  int s = eli[l], d = eli[L + l];
  const float4* a = (const float4*)(h + (size_t)s * 64);
  const float4* b = (const float4*)(h + (size_t)d * 64);
  const float4* wp = (const float4*)Wp;
  float acc = bp[0] + bp[1];
#pragma unroll
  for (int i = 0; i < 16; ++i) {
    float4 u = a[i], v = b[i];
    float4 w0 = wp[2 * i];
    float4 w1 = wp[2 * i + 1];
    acc = fmaf(u.x * v.x, w0.x + w0.y, acc);
    acc = fmaf(u.y * v.y, w0.z + w0.w, acc);
    acc = fmaf(u.z * v.z, w1.x + w1.y, acc);
    acc = fmaf(u.w * v.w, w1.z + w1.w, acc);
  }
  out[l] = acc;
}

static inline int cdiv(long long a, int b) { return (int)((a + b - 1) / b); }

extern "C" void kernel_launch(void* const* d_in, const int* in_sizes, int n_in,
                              void* d_out, int out_size, void* d_ws, size_t ws_size,
                              hipStream_t stream) {
  const float* x    = (const float*)d_in[0];
  const int*   ei   = (const int*)d_in[1];
  const int*   eli  = (const int*)d_in[2];
  const float* Wl1  = (const float*)d_in[3];
  const float* Wr1  = (const float*)d_in[4];
  const float* att1 = (const float*)d_in[5];
  const float* b1   = (const float*)d_in[6];
  const float* Wl2  = (const float*)d_in[7];
  const float* Wr2  = (const float*)d_in[8];
  const float* att2 = (const float*)d_in[9];
  const float* b2   = (const float*)d_in[10];
  const float* Wp   = (const float*)d_in[11];
  const float* bp   = (const float*)d_in[12];
  float* out = (float*)d_out;

  const int N = in_sizes[0] / 128;
  const int E = in_sizes[1] / 2;
  const int L = in_sizes[2] / 2;
  const int T = E + N;
  const int NC = cdiv(N, 256);

  // workspace layout
  float* A = (float*)d_ws;            // [N*96] xl1, later xr2
  float* B = A + (size_t)N * 96;      // [N*96] xr1, later xl2
  float* C = B + (size_t)N * 96;      // [N*96] h1, later h2
  int* deg    = (int*)(C + (size_t)N * 96);  // [N]
  int* cnt    = deg + N;                     // [N] (adjacent to deg: single memset)
  int* rowptr = cnt + N;                     // [N+1]
  int* ebuf   = rowptr + N + 1;              // [T]
  int* psum   = ebuf + T;                    // [NC]

  const int BS = 256;
  const int GB32 = cdiv(N, 32);  // BM=32 GEMM blocks

  // ---------------- CSR build (once, shared by both layers) ----------------
  (void)hipMemsetAsync(deg, 0, (size_t)(2 * N) * 4, stream);  // deg + cnt
  hist_kernel<<<cdiv(T, BS), BS, 0, stream>>>(ei, deg, E, N);
  chunk_sum_kernel<<<NC, 256, 0, stream>>>(deg, psum, N);
  scan_chunks_kernel<<<1, 256, 0, stream>>>(psum, NC);
  scan_final_kernel<<<NC, 256, 0, stream>>>(deg, psum, rowptr, N);
  fill_kernel<<<cdiv(T, BS), BS, 0, stream>>>(ei, cnt, rowptr, ebuf, E, N);

  // ---------------- layer 1 (128 -> 96) ----------------
  gemm2_kernel<128, 96, 16, 32, 192><<<GB32, 192, 0, stream>>>(x, Wl1, Wr1, A, B, N);
  gat_fused_kernel<96><<<cdiv(N, BS / 64), BS, 0, stream>>>(A, B, rowptr, ebuf, att1, b1, C, N);

  // ---------------- layer 2 (96 -> 64) ----------------
  gemm2_kernel<96, 64, 16, 32, 128><<<GB32, 128, 0, stream>>>(C, Wl2, Wr2, B, A, N);
  gat_fused_kernel<64><<<cdiv(N, BS / 64), BS, 0, stream>>>(B, A, rowptr, ebuf, att2, b2, C, N);

  // ---------------- link predictor ----------------
  predict_kernel<<<cdiv(L, BS), BS, 0, stream>>>(C, eli, Wp, bp, out, L);
}

// Round 17
// 263.838 us; speedup vs baseline: 1.0817x; 1.0817x over previous
//
#include <hip/hip_runtime.h>
#include <hip/hip_fp16.h>

#define NEG_SLOPE 0.2f

__device__ __forceinline__ __half2 u2h2(unsigned u) {
  union { unsigned u; __half2 h; } cv; cv.u = u; return cv.h;
}
__device__ __forceinline__ unsigned h22u(__half2 h) {
  union { unsigned u; __half2 h; } cv; cv.h = h; return cv.u;
}

// ---------- dual-output fp32 GEMM: Y1(fp16)=X@W1, Y2(fp32)=X@W2 ----------
// Y1 is the gather table for gat_fused -> stored fp16 to halve gather bytes.
template<int K, int H, int BK, int BM, int NT>
__global__ __launch_bounds__(NT) void gemm2_kernel(const float* __restrict__ X,
                                                   const float* __restrict__ W1,
                                                   const float* __restrict__ W2,
                                                   __half* __restrict__ Y1,
                                                   float* __restrict__ Y2, int n) {
  constexpr int CG = H / 4;   // col groups
  constexpr int RG = BM / 4;  // row groups
  static_assert(CG * RG == NT, "thread grid mismatch");
  __shared__ alignas(16) float Xs[BK][BM + 4];
  __shared__ alignas(16) float Ws1[BK][H];
  __shared__ alignas(16) float Ws2[BK][H];
  const int tid = threadIdx.x;
  const int row0 = blockIdx.x * BM;
  const int cg = tid % CG, rg = tid / CG;
  float acc1[4][4] = {};
  float acc2[4][4] = {};

  for (int kc = 0; kc < K; kc += BK) {
    for (int i = tid; i < BK * H / 4; i += NT) {
      ((float4*)&Ws1[0][0])[i] = ((const float4*)(W1 + (size_t)kc * H))[i];
      ((float4*)&Ws2[0][0])[i] = ((const float4*)(W2 + (size_t)kc * H))[i];
    }
    for (int i = tid; i < BM * (BK / 4); i += NT) {
      int r = i / (BK / 4), kq = i % (BK / 4);
      int gr = row0 + r; if (gr >= n) gr = n - 1;
      float4 v = ((const float4*)(X + (size_t)gr * K + kc))[kq];
      Xs[kq * 4 + 0][r] = v.x;
      Xs[kq * 4 + 1][r] = v.y;
      Xs[kq * 4 + 2][r] = v.z;
      Xs[kq * 4 + 3][r] = v.w;
    }
    __syncthreads();
#pragma unroll 8
    for (int k = 0; k < BK; ++k) {
      float4 xa = *(const float4*)&Xs[k][rg * 4];
      float4 wa = *(const float4*)&Ws1[k][cg * 4];
      float4 wb = *(const float4*)&Ws2[k][cg * 4];
#pragma unroll
      for (int i = 0; i < 4; ++i) {
        float xi = (i == 0) ? xa.x : (i == 1) ? xa.y : (i == 2) ? xa.z : xa.w;
        acc1[i][0] = fmaf(xi, wa.x, acc1[i][0]);
        acc1[i][1] = fmaf(xi, wa.y, acc1[i][1]);
        acc1[i][2] = fmaf(xi, wa.z, acc1[i][2]);
        acc1[i][3] = fmaf(xi, wa.w, acc1[i][3]);
        acc2[i][0] = fmaf(xi, wb.x, acc2[i][0]);
        acc2[i][1] = fmaf(xi, wb.y, acc2[i][1]);
        acc2[i][2] = fmaf(xi, wb.z, acc2[i][2]);
        acc2[i][3] = fmaf(xi, wb.w, acc2[i][3]);
      }
    }
    __syncthreads();
  }
  const int c0 = cg * 4;
#pragma unroll
  for (int i = 0; i < 4; ++i) {
    int gr = row0 + rg * 4 + i;
    if (gr < n) {
      uint2 uv;
      uv.x = h22u(__floats2half2_rn(acc1[i][0], acc1[i][1]));
      uv.y = h22u(__floats2half2_rn(acc1[i][2], acc1[i][3]));
      *(uint2*)(Y1 + (size_t)gr * H + c0) = uv;
      *(float4*)(Y2 + (size_t)gr * H + c0) = make_float4(acc2[i][0], acc2[i][1], acc2[i][2], acc2[i][3]);
    }
  }
}

// ---------- CSR build: histogram of dst ----------
__global__ void hist_kernel(const int* __restrict__ ei, int* __restrict__ deg, int nE, int nN) {
  int t = blockIdx.x * blockDim.x + threadIdx.x;
  if (t >= nE + nN) return;
  int d = (t < nE) ? ei[nE + t] : (t - nE);
  atomicAdd(&deg[d], 1);
}

// ---------- parallel scan, step 1: per-256-chunk sums ----------
__global__ void chunk_sum_kernel(const int* __restrict__ deg, int* __restrict__ psum, int n) {
  int c = blockIdx.x;
  int i = c * 256 + threadIdx.x;
  int lane = threadIdx.x & 63, wid = threadIdx.x >> 6;
  int v = (i < n) ? deg[i] : 0;
#pragma unroll
  for (int off = 32; off; off >>= 1) v += __shfl_xor(v, off);
  __shared__ int ws[4];
  if (lane == 0) ws[wid] = v;
  __syncthreads();
  if (threadIdx.x == 0) psum[c] = ws[0] + ws[1] + ws[2] + ws[3];
}

// ---------- block-wide inclusive scan helper (256 threads) ----------
__device__ __forceinline__ int block_incl_scan_256(int v) {
  int lane = threadIdx.x & 63, wid = threadIdx.x >> 6;
#pragma unroll
  for (int off = 1; off < 64; off <<= 1) {
    int t = __shfl_up(v, off);
    if (lane >= off) v += t;
  }
  __shared__ int wsum[4];
  if (lane == 63) wsum[wid] = v;
  __syncthreads();
  int add = 0;
  for (int w = 0; w < wid; ++w) add += wsum[w];
  return v + add;
}

// ---------- parallel scan, step 2: inclusive scan of chunk sums (nc <= 256) ----------
__global__ void scan_chunks_kernel(int* __restrict__ psum, int nc) {
  int i = threadIdx.x;
  int v = (i < nc) ? psum[i] : 0;
  int incl = block_incl_scan_256(v);
  if (i < nc) psum[i] = incl;
}

// ---------- parallel scan, step 3: intra-chunk scan + chunk offset -> rowptr ----------
__global__ void scan_final_kernel(const int* __restrict__ deg, const int* __restrict__ psum,
                                  int* __restrict__ rowptr, int n) {
  int c = blockIdx.x;
  int i = c * 256 + threadIdx.x;
  int v = (i < n) ? deg[i] : 0;
  int incl = block_incl_scan_256(v);
  int off = (c > 0) ? psum[c - 1] : 0;
  if (i < n) rowptr[i + 1] = off + incl;
  if (i == 0) rowptr[0] = 0;
}

// ---------- CSR build: fill src ids into dst buckets ----------
__global__ void fill_kernel(const int* __restrict__ ei, int* __restrict__ cnt,
                            const int* __restrict__ rowptr, int* __restrict__ ebuf,
                            int nE, int nN) {
  int t = blockIdx.x * blockDim.x + threadIdx.x;
  if (t >= nE + nN) return;
  int s, d;
  if (t < nE) { s = ei[t]; d = ei[nE + t]; } else { s = t - nE; d = s; }
  int pos = rowptr[d] + atomicAdd(&cnt[d], 1);
  ebuf[pos] = s;
}

// ---------- fused GATv2 layer: wave per dst, 4x16-lane edge groups ----------
// Round-13 structure (1 edge/group-iter, occupancy-bound optimum); XL table
// gathered as fp16 (half the fetch bytes of the dominant random-gather).
// OutT=float for layer 1 (feeds GEMM), __half for layer 2 (feeds predict).
template<int H, typename OutT>
__global__ void gat_fused_kernel(const __half* __restrict__ XL, const float* __restrict__ XR,
                                 const int* __restrict__ rowptr, const int* __restrict__ ebuf,
                                 const float* __restrict__ att, const float* __restrict__ bias,
                                 OutT* __restrict__ out, int nN) {
  constexpr bool HAS2 = (H > 64);
  int lane = threadIdx.x & 63;
  int wid = threadIdx.x >> 6;
  int d = blockIdx.x * (blockDim.x >> 6) + wid;
  if (d >= nN) return;
  int g = lane >> 4;   // edge group 0..3
  int ll = lane & 15;  // lane within group
  const int cA = ll * 4;
  const int cB = 64 + ll * 2;

  const float* xrrow = XR + (size_t)d * H;
  float4 xr4 = *(const float4*)(xrrow + cA);
  float4 a4 = *(const float4*)(att + cA);
  float4 s4 = make_float4(a4.x * NEG_SLOPE, a4.y * NEG_SLOPE, a4.z * NEG_SLOPE, a4.w * NEG_SLOPE);
  float2 xr2 = make_float2(0.f, 0.f), a2 = make_float2(0.f, 0.f), s2 = make_float2(0.f, 0.f);
  if constexpr (HAS2) {
    xr2 = *(const float2*)(xrrow + cB);
    a2 = *(const float2*)(att + cB);
    s2 = make_float2(a2.x * NEG_SLOPE, a2.y * NEG_SLOPE);
  }

  float m = -1e30f, den = 0.f;
  float4 o4 = make_float4(0.f, 0.f, 0.f, 0.f);
  float2 o2 = make_float2(0.f, 0.f);

  int beg = rowptr[d], end = rowptr[d + 1];
  int i = beg + g;
  int s = (i < end) ? ebuf[i] : 0;
  while (i < end) {
    int inext = i + 4;
    int snext = (inext < end) ? ebuf[inext] : 0;
    const __half* R = XL + (size_t)s * H;
    uint2 ua = *(const uint2*)(R + cA);
    float2 fa0 = __half22float2(u2h2(ua.x));
    float2 fa1 = __half22float2(u2h2(ua.y));
    float4 x4 = make_float4(fa0.x, fa0.y, fa1.x, fa1.y);
    float2 x2 = make_float2(0.f, 0.f);
    if constexpr (HAS2) {
      unsigned ub = *(const unsigned*)(R + cB);
      x2 = __half22float2(u2h2(ub));
    }
    float f, p;
    f = x4.x + xr4.x; p = fmaf(fmaxf(f, 0.f), a4.x, fminf(f, 0.f) * s4.x);
    f = x4.y + xr4.y; p = fmaf(fmaxf(f, 0.f), a4.y, fmaf(fminf(f, 0.f), s4.y, p));
    f = x4.z + xr4.z; p = fmaf(fmaxf(f, 0.f), a4.z, fmaf(fminf(f, 0.f), s4.z, p));
    f = x4.w + xr4.w; p = fmaf(fmaxf(f, 0.f), a4.w, fmaf(fminf(f, 0.f), s4.w, p));
    if constexpr (HAS2) {
      f = x2.x + xr2.x; p = fmaf(fmaxf(f, 0.f), a2.x, fmaf(fminf(f, 0.f), s2.x, p));
      f = x2.y + xr2.y; p = fmaf(fmaxf(f, 0.f), a2.y, fmaf(fminf(f, 0.f), s2.y, p));
    }
    p += __shfl_xor(p, 1);
    p += __shfl_xor(p, 2);
    p += __shfl_xor(p, 4);
    p += __shfl_xor(p, 8);
    if (p > m) {
      float scl = __expf(m - p);
      den *= scl;
      o4.x *= scl; o4.y *= scl; o4.z *= scl; o4.w *= scl;
      if constexpr (HAS2) { o2.x *= scl; o2.y *= scl; }
      m = p;
    }
    float w = __expf(p - m);
    den += w;
    o4.x = fmaf(w, x4.x, o4.x); o4.y = fmaf(w, x4.y, o4.y);
    o4.z = fmaf(w, x4.z, o4.z); o4.w = fmaf(w, x4.w, o4.w);
    if constexpr (HAS2) { o2.x = fmaf(w, x2.x, o2.x); o2.y = fmaf(w, x2.y, o2.y); }
    i = inext;
    s = snext;
  }

  // merge the 4 groups (flash-style), xor 16 then xor 32
#pragma unroll
  for (int msk = 16; msk <= 32; msk <<= 1) {
    float m2 = __shfl_xor(m, msk);
    float den2 = __shfl_xor(den, msk);
    float q0 = __shfl_xor(o4.x, msk), q1 = __shfl_xor(o4.y, msk);
    float q2 = __shfl_xor(o4.z, msk), q3 = __shfl_xor(o4.w, msk);
    float q4 = 0.f, q5 = 0.f;
    if constexpr (HAS2) { q4 = __shfl_xor(o2.x, msk); q5 = __shfl_xor(o2.y, msk); }
    float M = fmaxf(m, m2);
    float sa = __expf(m - M), sb = __expf(m2 - M);
    den = den * sa + den2 * sb;
    o4.x = o4.x * sa + q0 * sb; o4.y = o4.y * sa + q1 * sb;
    o4.z = o4.z * sa + q2 * sb; o4.w = o4.w * sa + q3 * sb;
    if constexpr (HAS2) { o2.x = o2.x * sa + q4 * sb; o2.y = o2.y * sa + q5 * sb; }
    m = M;
  }

  if (g == 0) {
    float inv = 1.f / (den + 1e-16f);
    float4 b4 = *(const float4*)(bias + cA);
    float4 y;
    y.x = fmaf(o4.x, inv, b4.x); y.x = y.x > 0.f ? y.x : 0.f;
    y.y = fmaf(o4.y, inv, b4.y); y.y = y.y > 0.f ? y.y : 0.f;
    y.z = fmaf(o4.z, inv, b4.z); y.z = y.z > 0.f ? y.z : 0.f;
    y.w = fmaf(o4.w, inv, b4.w); y.w = y.w > 0.f ? y.w : 0.f;
    if constexpr (__hip_internal::is_same<OutT, float>::value) {
      *(float4*)(out + (size_t)d * H + cA) = y;
      if constexpr (HAS2) {
        float2 b2 = *(const float2*)(bias + cB);
        float2 z;
        z.x = fmaf(o2.x, inv, b2.x); z.x = z.x > 0.f ? z.x : 0.f;
        z.y = fmaf(o2.y, inv, b2.y); z.y = z.y > 0.f ? z.y : 0.f;
        *(float2*)(out + (size_t)d * H + cB) = z;
      }
    } else {
      uint2 uv;
      uv.x = h22u(__floats2half2_rn(y.x, y.y));
      uv.y = h22u(__floats2half2_rn(y.z, y.w));
      *(uint2*)((__half*)out + (size_t)d * H + cA) = uv;
      // H==64 for the half path: no cB tail
    }
  }
}

// ---------- out[l] = sum_k hs[k]*hd[k]*(Wp[k,0]+Wp[k,1]) + bp0+bp1, fp16 h ----------
__global__ void predict_kernel(const __half* __restrict__ h, const int* __restrict__ eli,
                               const float* __restrict__ Wp, const float* __restrict__ bp,
                               float* __restrict__ out, int L) {
  int l = blockIdx.x * blockDim.x + threadIdx.x;
  if (l >= L) return;
  int s = eli[l], d = eli[L + l];
  const uint4* a4 = (const uint4*)(h + (size_t)s * 64);  // 8 halves per uint4
  const uint4* b4 = (const uint4*)(h + (size_t)d * 64);
  const float4* wp4 = (const float4*)Wp;  // wp4[i] = (w[2i,0],w[2i,1],w[2i+1,0],w[2i+1,1])
  float acc = bp[0] + bp[1];
#pragma unroll
  for (int i = 0; i < 8; ++i) {
    uint4 ua = a4[i], ub = b4[i];
    float2 u0 = __half22float2(u2h2(ua.x)), v0 = __half22float2(u2h2(ub.x));
    float2 u1 = __half22float2(u2h2(ua.y)), v1 = __half22float2(u2h2(ub.y));
    float2 u2_ = __half22float2(u2h2(ua.z)), v2 = __half22float2(u2h2(ub.z));
    float2 u3 = __half22float2(u2h2(ua.w)), v3 = __half22float2(u2h2(ub.w));
    float4 w0 = wp4[4 * i + 0];  // k = 8i, 8i+1
    float4 w1 = wp4[4 * i + 1];  // k = 8i+2, 8i+3
    float4 w2 = wp4[4 * i + 2];  // k = 8i+4, 8i+5
    float4 w3 = wp4[4 * i + 3];  // k = 8i+6, 8i+7
    acc = fmaf(u0.x * v0.x, w0.x + w0.y, acc);
    acc = fmaf(u0.y * v0.y, w0.z + w0.w, acc);
    acc = fmaf(u1.x * v1.x, w1.x + w1.y, acc);
    acc = fmaf(u1.y * v1.y, w1.z + w1.w, acc);
    acc = fmaf(u2_.x * v2.x, w2.x + w2.y, acc);
    acc = fmaf(u2_.y * v2.y, w2.z + w2.w, acc);
    acc = fmaf(u3.x * v3.x, w3.x + w3.y, acc);
    acc = fmaf(u3.y * v3.y, w3.z + w3.w, acc);
  }
  out[l] = acc;
}

static inline int cdiv(long long a, int b) { return (int)((a + b - 1) / b); }

extern "C" void kernel_launch(void* const* d_in, const int* in_sizes, int n_in,
                              void* d_out, int out_size, void* d_ws, size_t ws_size,
                              hipStream_t stream) {
  const float* x    = (const float*)d_in[0];
  const int*   ei   = (const int*)d_in[1];
  const int*   eli  = (const int*)d_in[2];
  const float* Wl1  = (const float*)d_in[3];
  const float* Wr1  = (const float*)d_in[4];
  const float* att1 = (const float*)d_in[5];
  const float* b1   = (const float*)d_in[6];
  const float* Wl2  = (const float*)d_in[7];
  const float* Wr2  = (const float*)d_in[8];
  const float* att2 = (const float*)d_in[9];
  const float* b2   = (const float*)d_in[10];
  const float* Wp   = (const float*)d_in[11];
  const float* bp   = (const float*)d_in[12];
  float* out = (float*)d_out;

  const int N = in_sizes[0] / 128;
  const int E = in_sizes[1] / 2;
  const int L = in_sizes[2] / 2;
  const int T = E + N;
  const int NC = cdiv(N, 256);

  // workspace layout
  __half* xlh = (__half*)d_ws;                          // [N*96] fp16 xl table (L1), [N*64] (L2)
  float* xr   = (float*)((char*)d_ws + (size_t)N * 96 * sizeof(__half));  // [N*96] / [N*64]
  float* h1   = xr + (size_t)N * 96;                    // [N*96] fp32 (GEMM L2 input)
  __half* h2  = (__half*)(h1 + (size_t)N * 96);         // [N*64] fp16 (predict input)
  int* deg    = (int*)(h2 + (size_t)N * 64);            // [N]
  int* cnt    = deg + N;                                // [N]
  int* rowptr = cnt + N;                                // [N+1]
  int* ebuf   = rowptr + N + 1;                         // [T]
  int* psum   = ebuf + T;                               // [NC]

  const int BS = 256;
  const int GB32 = cdiv(N, 32);  // BM=32 GEMM blocks

  // ---------------- CSR build (once, shared by both layers) ----------------
  (void)hipMemsetAsync(deg, 0, (size_t)(2 * N) * 4, stream);  // deg + cnt
  hist_kernel<<<cdiv(T, BS), BS, 0, stream>>>(ei, deg, E, N);
  chunk_sum_kernel<<<NC, 256, 0, stream>>>(deg, psum, N);
  scan_chunks_kernel<<<1, 256, 0, stream>>>(psum, NC);
  scan_final_kernel<<<NC, 256, 0, stream>>>(deg, psum, rowptr, N);
  fill_kernel<<<cdiv(T, BS), BS, 0, stream>>>(ei, cnt, rowptr, ebuf, E, N);

  // ---------------- layer 1 (128 -> 96) ----------------
  gemm2_kernel<128, 96, 16, 32, 192><<<GB32, 192, 0, stream>>>(x, Wl1, Wr1, xlh, xr, N);
  gat_fused_kernel<96, float><<<cdiv(N, BS / 64), BS, 0, stream>>>(xlh, xr, rowptr, ebuf, att1, b1, h1, N);

  // ---------------- layer 2 (96 -> 64) ----------------
  gemm2_kernel<96, 64, 16, 32, 128><<<GB32, 128, 0, stream>>>(h1, Wl2, Wr2, xlh, xr, N);
  gat_fused_kernel<64, __half><<<cdiv(N, BS / 64), BS, 0, stream>>>(xlh, xr, rowptr, ebuf, att2, b2, h2, N);

  // ---------------- link predictor ----------------
  predict_kernel<<<cdiv(L, BS), BS, 0, stream>>>(h2, eli, Wp, bp, out, L);
}